// Round 16
// baseline (117.397 us; speedup 1.0000x reference)
//
#include <hip/hip_runtime.h>
#include <math.h>

#define KNN 16
#define DIM 128
#define BQ 256
#define NDB 100000
#define GRID 512                 // k_pass0 blocks
#define RPP 32                   // rows per chunk
#define NCHUNK 3125              // 100000 / 32, exact
#define LONGB 53                 // blocks with 7 chunks (rest 6)
#define XB_STR 136               // ushorts per LDS B-row (128 + 8 pad)
#define MREG 8                   // GRID / 64
#define CAPS 256                 // k_sel candidate cap (worst case ~64)
#define TAU_INV 10.0f
#define EPSC 1e-8f
#define FBIG 3.402823e38f

typedef float f32x4 __attribute__((ext_vector_type(4)));
typedef __bf16 bf16x8 __attribute__((ext_vector_type(8)));
typedef unsigned short ushort;
typedef ushort ushort8 __attribute__((ext_vector_type(8)));

__device__ __forceinline__ ushort f32_to_bf16_rne(float v) {
    unsigned bits = __float_as_uint(v);
    return (ushort)((bits + 0x7FFFu + ((bits >> 16) & 1u)) >> 16);
}
// pack: truncate low 8 mantissa bits, embed 8-bit source id (unique, order-preserving enough)
__device__ __forceinline__ float packv(float v, int id) {
    return __uint_as_float((__float_as_uint(v) & 0xFFFFFF00u) | (unsigned)id);
}

// ---------------- Kernel A: Tq = q_batch @ W (f32 + bf16 copies) ----------------
__global__ void k_tq(const float* __restrict__ qb, const float* __restrict__ W,
                     float* __restrict__ Tq, ushort* __restrict__ Tqb) {
    int b = blockIdx.x, c = threadIdx.x;   // 128 threads
    __shared__ float qs[DIM];
    qs[c] = qb[b * DIM + c];
    __syncthreads();
    float acc = 0.f;
#pragma unroll 8
    for (int k = 0; k < DIM; ++k) acc = fmaf(qs[k], W[k * DIM + c], acc);
    Tq[b * DIM + c] = acc;
    Tqb[b * DIM + c] = f32_to_bf16_rne(acc);
}

// ---------------- Kernel B: single MFMA pass, per-(block,query) packed top-4 ----------------
__global__ __launch_bounds__(512, 2)
void k_pass0(const ushort* __restrict__ Tqb, const float* __restrict__ X,
             float* __restrict__ cand, float* __restrict__ blkmin_t) {
    __shared__ ushort xb[2][RPP * XB_STR];
    __shared__ float xsq_lds[2][RPP];
    const int t = threadIdx.x;
    const int w = t >> 6, lane = t & 63;
    const int la = lane >> 4, lb = lane & 15;
    const int sr = t >> 4, sc = t & 15;
    const int bid = blockIdx.x;
    const int nph = (bid < LONGB) ? 7 : 6;

    bf16x8 afr[2][4];              // 32 queries x K=128 = 32 VGPRs, resident
#pragma unroll
    for (int mt = 0; mt < 2; ++mt)
#pragma unroll
        for (int ks = 0; ks < 4; ++ks)
            afr[mt][ks] = *reinterpret_cast<const bf16x8*>(
                Tqb + (size_t)(w * 32 + mt * 16 + lb) * DIM + ks * 32 + la * 8);

    {   // prolog: stage chunk 0 (f32 -> bf16 + xsq)
        const int rbase = bid * RPP;
        const float4* src = reinterpret_cast<const float4*>(X + (size_t)(rbase + sr) * DIM + sc * 8);
        float4 v0 = src[0], v1 = src[1];
        ushort8 o;
        o[0]=f32_to_bf16_rne(v0.x); o[1]=f32_to_bf16_rne(v0.y); o[2]=f32_to_bf16_rne(v0.z); o[3]=f32_to_bf16_rne(v0.w);
        o[4]=f32_to_bf16_rne(v1.x); o[5]=f32_to_bf16_rne(v1.y); o[6]=f32_to_bf16_rne(v1.z); o[7]=f32_to_bf16_rne(v1.w);
        *reinterpret_cast<ushort8*>(&xb[0][sr * XB_STR + sc * 8]) = o;
        float s = v0.x*v0.x + v0.y*v0.y + v0.z*v0.z + v0.w*v0.w
                + v1.x*v1.x + v1.y*v1.y + v1.z*v1.z + v1.w*v1.w;
        s += __shfl_xor(s, 1, 16); s += __shfl_xor(s, 2, 16);
        s += __shfl_xor(s, 4, 16); s += __shfl_xor(s, 8, 16);
        if (sc == 0) xsq_lds[0][sr] = s;
    }
    asm volatile("s_waitcnt lgkmcnt(0)" ::: "memory");
    __builtin_amdgcn_s_barrier();

    float t4_0[2][4], t4_1[2][4], t4_2[2][4], t4_3[2][4];
#pragma unroll
    for (int mt = 0; mt < 2; ++mt)
#pragma unroll
        for (int r = 0; r < 4; ++r) {
            t4_0[mt][r] = FBIG; t4_1[mt][r] = FBIG;
            t4_2[mt][r] = FBIG; t4_3[mt][r] = FBIG;
        }

#pragma unroll 1
    for (int p = 0; p < nph; ++p) {
        const int cur = p & 1, nxt = cur ^ 1;
        const int rb2 = (bid + ((p + 1) << 9)) << 5;
        float4 q0, q1;
        if (p + 1 < nph) {
            const float4* s2 = reinterpret_cast<const float4*>(X + (size_t)(rb2 + sr) * DIM + sc * 8);
            q0 = s2[0]; q1 = s2[1];
        }
#pragma unroll
        for (int nt = 0; nt < 2; ++nt) {
            const int row = nt * 16 + lb;
            bf16x8 bfr[4];
#pragma unroll
            for (int ks = 0; ks < 4; ++ks)
                bfr[ks] = *reinterpret_cast<const bf16x8*>(
                    &xb[cur][row * XB_STR + ks * 32 + la * 8]);
            const float xs = xsq_lds[cur][row];
            const int id = (((p << 1) | nt) << 4) | lb;   // 8-bit source id
#pragma unroll
            for (int mt = 0; mt < 2; ++mt) {
                f32x4 acc = {0.f, 0.f, 0.f, 0.f};
#pragma unroll
                for (int ks = 0; ks < 4; ++ks)
                    acc = __builtin_amdgcn_mfma_f32_16x16x32_bf16(afr[mt][ks], bfr[ks], acc, 0, 0, 0);
#pragma unroll
                for (int r = 0; r < 4; ++r) {
                    float tv = packv(fmaf(-2.f, acc[r], xs), id);
                    float b0 = fminf(t4_0[mt][r], tv); tv = fmaxf(t4_0[mt][r], tv);
                    float b1 = fminf(t4_1[mt][r], tv); tv = fmaxf(t4_1[mt][r], tv);
                    float b2 = fminf(t4_2[mt][r], tv); tv = fmaxf(t4_2[mt][r], tv);
                    float b3 = fminf(t4_3[mt][r], tv);
                    t4_0[mt][r] = b0; t4_1[mt][r] = b1;
                    t4_2[mt][r] = b2; t4_3[mt][r] = b3;
                }
            }
        }
        if (p + 1 < nph) {   // write-late staging of next chunk
            ushort8 o;
            o[0]=f32_to_bf16_rne(q0.x); o[1]=f32_to_bf16_rne(q0.y); o[2]=f32_to_bf16_rne(q0.z); o[3]=f32_to_bf16_rne(q0.w);
            o[4]=f32_to_bf16_rne(q1.x); o[5]=f32_to_bf16_rne(q1.y); o[6]=f32_to_bf16_rne(q1.z); o[7]=f32_to_bf16_rne(q1.w);
            *reinterpret_cast<ushort8*>(&xb[nxt][sr * XB_STR + sc * 8]) = o;
            float s = q0.x*q0.x + q0.y*q0.y + q0.z*q0.z + q0.w*q0.w
                    + q1.x*q1.x + q1.y*q1.y + q1.z*q1.z + q1.w*q1.w;
            s += __shfl_xor(s, 1, 16); s += __shfl_xor(s, 2, 16);
            s += __shfl_xor(s, 4, 16); s += __shfl_xor(s, 8, 16);
            if (sc == 0) xsq_lds[nxt][sr] = s;
            asm volatile("s_waitcnt lgkmcnt(0)" ::: "memory");
            __builtin_amdgcn_s_barrier();
        }
    }

    // epilogue: merge 16 lanes' sorted-4 lists (butterfly; bitonic half-clean + sort4)
#pragma unroll
    for (int mt = 0; mt < 2; ++mt)
#pragma unroll
        for (int r = 0; r < 4; ++r) {
            float a0 = t4_0[mt][r], a1 = t4_1[mt][r], a2 = t4_2[mt][r], a3 = t4_3[mt][r];
#pragma unroll
            for (int m = 1; m <= 8; m <<= 1) {
                float b0 = __shfl_xor(a0, m, 16), b1 = __shfl_xor(a1, m, 16);
                float b2 = __shfl_xor(a2, m, 16), b3 = __shfl_xor(a3, m, 16);
                float l0 = fminf(a0, b3), l1 = fminf(a1, b2);
                float l2 = fminf(a2, b1), l3 = fminf(a3, b0);
                float u;
                u = fminf(l0, l2); l2 = fmaxf(l0, l2); l0 = u;
                u = fminf(l1, l3); l3 = fmaxf(l1, l3); l1 = u;
                u = fminf(l0, l1); l1 = fmaxf(l0, l1); l0 = u;
                u = fminf(l2, l3); l3 = fmaxf(l2, l3); l2 = u;
                a0 = l0; a1 = l1; a2 = l2; a3 = l3;
            }
            if (lb == 0) {
                const int q = w * 32 + mt * 16 + la * 4 + r;
                f32x4 o4 = {a0, a1, a2, a3};
                *reinterpret_cast<f32x4*>(cand + (size_t)q * (GRID * 4) + bid * 4) = o4;
                blkmin_t[(size_t)q * GRID + bid] = a0;
            }
        }
}

// ---------------- Kernel C: tau + filter + rank select + exact l2 + softmax + KL ----------------
__global__ __launch_bounds__(256)
void k_sel(const float* __restrict__ cand, const float* __restrict__ blkmin_t,
           const float* __restrict__ Tq, const float* __restrict__ X,
           const int* __restrict__ q_indices,
           const int* __restrict__ pre_indices,
           const float* __restrict__ pre_weights,
           float* __restrict__ klv) {
    const int q = blockIdx.x, t = threadIdx.x;
    __shared__ float tau_s;
    __shared__ int cnt_s;
    __shared__ float cv[CAPS]; __shared__ int ce[CAPS];
    __shared__ int post_idx[KNN];
    __shared__ float l2s[KNN];
    __shared__ float post_w[KNN];
    __shared__ int u_idx[2 * KNN]; __shared__ float u_p[2 * KNN]; __shared__ float u_q[2 * KNN];
    __shared__ int cnt2_s;

    if (t == 0) cnt_s = 0;
    if (t < KNN) post_idx[t] = 0;
    if (t < 64) {   // wave 0: tau = exact 16th smallest packed block-min
        float m[MREG];
#pragma unroll
        for (int k = 0; k < MREG; ++k)
            m[k] = blkmin_t[(size_t)q * GRID + t + (k << 6)];
        float tv = FBIG;
        for (int e = 0; e < KNN; ++e) {
            float best = m[0];
#pragma unroll
            for (int k = 1; k < MREG; ++k) best = fminf(best, m[k]);
            float b = best;
#pragma unroll
            for (int s = 1; s < 64; s <<= 1) b = fminf(b, __shfl_xor(b, s, 64));
            tv = b;
            unsigned long long has = __ballot(best == b);
            int src = (int)__builtin_ctzll(has);
            if (t == src) {   // remove exactly one instance
                bool dn = false;
#pragma unroll
                for (int k = 0; k < MREG; ++k) {
                    bool hit = !dn && (m[k] == b);
                    if (hit) { m[k] = FBIG; dn = true; }
                }
            }
        }
        if (t == 0) tau_s = tv;
    }
    __syncthreads();
    const float tau = tau_s;

    for (int e = t; e < GRID * 4; e += 256) {
        float pv = cand[(size_t)q * (GRID * 4) + e];
        if (pv <= tau) {
            int pos = atomicAdd(&cnt_s, 1);
            if (pos < CAPS) { cv[pos] = pv; ce[pos] = e; }
        }
    }
    __syncthreads();
    int n = cnt_s; n = (n > CAPS) ? CAPS : n;

    for (int e = t; e < n; e += 256) {
        float v = cv[e]; int id = ce[e];
        int r = 0;
        for (int i2 = 0; i2 < n; ++i2) {
            float vi = cv[i2];
            r += (vi < v) || (vi == v && ce[i2] < id);
        }
        if (r < KNN) {
            int bid = id >> 2;
            int sid = __float_as_uint(v) & 255;           // ((p*2+nt)<<4)|lb
            int j = (bid + (sid >> 5) * GRID) * RPP + ((sid >> 4) & 1) * 16 + (sid & 15);
            post_idx[r] = j;
        }
    }
    __syncthreads();

    {   // exact f32 l2 for the selected 16 (16 threads x 8 dims each)
        int nn = t >> 4, l = t & 15;
        int idx = post_idx[nn];
        idx = (idx < 0) ? 0 : ((idx >= NDB) ? NDB - 1 : idx);
        const float* tr = Tq + q * DIM + l * 8;
        const float* xr = X + (size_t)idx * DIM + l * 8;
        float s = 0.f;
#pragma unroll
        for (int kk = 0; kk < 8; ++kk) { float df = tr[kk] - xr[kk]; s = fmaf(df, df, s); }
#pragma unroll
        for (int m = 1; m < 16; m <<= 1) s += __shfl_xor(s, m, 64);
        if (l == 0) l2s[nn] = s;
    }
    __syncthreads();

    if (t < 64) {   // wave-parallel softmax over the 16 l2 values
        float v = (t < KNN) ? (-l2s[t] * TAU_INV) : -FBIG;
        float mx = v;
#pragma unroll
        for (int m = 1; m < 16; m <<= 1) mx = fmaxf(mx, __shfl_xor(mx, m, 64));
        float e = (t < KNN) ? expf(v - mx) : 0.f;
        float sum = e;
#pragma unroll
        for (int m = 1; m < 16; m <<= 1) sum += __shfl_xor(sum, m, 64);
        if (t < KNN) post_w[t] = e / sum;
    }
    __syncthreads();

    if (t == 0) {   // union build: serial (order-sensitive last-wins)
        int qi = q_indices[q];
        int cnt2 = KNN;
        for (int i = 0; i < KNN; ++i) { u_idx[i] = post_idx[i]; u_q[i] = post_w[i]; u_p[i] = 0.f; }
        for (int m = 0; m < KNN; ++m) {
            int pi = pre_indices[qi * KNN + m];
            float pwm = pre_weights[qi * KNN + m];
            int f = -1;
            for (int s2 = 0; s2 < cnt2; ++s2) if (u_idx[s2] == pi) { f = s2; break; }
            if (f >= 0) u_p[f] = pwm;
            else { u_idx[cnt2] = pi; u_p[cnt2] = pwm; u_q[cnt2] = 0.f; ++cnt2; }
        }
        cnt2_s = cnt2;
    }
    __syncthreads();

    if (t < 64) {   // wave-parallel KL: T/Zp - log Zp + log Zq
        int cnt2 = cnt2_s;
        float pe = 0.f, qe = 0.f, te = 0.f;
        if (t < cnt2) {
            pe = fmaxf(u_p[t], EPSC);
            qe = fmaxf(u_q[t], EPSC);
            te = pe * (logf(pe) - logf(qe));
        }
        float Zp = pe, Zq = qe, T = te;
#pragma unroll
        for (int m = 1; m < 64; m <<= 1) {
            Zp += __shfl_xor(Zp, m, 64);
            Zq += __shfl_xor(Zq, m, 64);
            T  += __shfl_xor(T, m, 64);
        }
        if (t == 0) klv[q] = T / Zp - logf(Zp) + logf(Zq);
    }
}

// ---------------- Kernel D: final reduction + outputs ----------------
__global__ void k_out(const float* __restrict__ kl, const float* __restrict__ W,
                      float* __restrict__ out) {
    int t = threadIdx.x;
    float s_kl = (t < BQ) ? kl[t] : 0.f;
    float s_w = 0.f;
    for (int i = t; i < DIM * DIM; i += 256) { float w = W[i]; s_w = fmaf(w, w, s_w); }
#pragma unroll
    for (int m = 32; m >= 1; m >>= 1) {
        s_kl += __shfl_xor(s_kl, m, 64);
        s_w += __shfl_xor(s_w, m, 64);
    }
    __shared__ float rk[4], rw[4];
    if ((t & 63) == 0) { rk[t >> 6] = s_kl; rw[t >> 6] = s_w; }
    __syncthreads();
    if (t == 0) {
        float kls = rk[0] + rk[1] + rk[2] + rk[3];
        float wss = rw[0] + rw[1] + rw[2] + rw[3];
        float knn = kls * (1.0f / BQ);
        float reg = 0.5f * wss;
        out[0] = 1.0f * knn + 1e-4f * reg;
        out[1] = 0.f;
        out[2] = knn;
    }
}

extern "C" void kernel_launch(void* const* d_in, const int* in_sizes, int n_in,
                              void* d_out, int out_size, void* d_ws, size_t ws_size,
                              hipStream_t stream) {
    const float* q_batch     = (const float*)d_in[0];
    const int*   q_indices   = (const int*)d_in[1];
    const float* X           = (const float*)d_in[2];
    const float* W           = (const float*)d_in[3];
    const int*   pre_indices = (const int*)d_in[4];
    const float* pre_weights = (const float*)d_in[5];

    char* ws = (char*)d_ws;
    float*  Tq      = (float*)(ws);                  // 128KB
    ushort* Tqb     = (ushort*)(ws + 131072);        // 64KB
    float*  klv     = (float*)(ws + 196608);         // 1KB
    float*  blkmint = (float*)(ws + 262144);         // 256*512*4 = 512KB
    float*  cand    = (float*)(ws + 1048576);        // 256*2048*4 = 2MB

    k_tq<<<dim3(BQ), dim3(DIM), 0, stream>>>(q_batch, W, Tq, Tqb);
    // BISECTION PROBE: k_pass0 launched TWICE (idempotent — identical deterministic
    // writes; 2nd completes before k_sel). Total delta vs R15 == pass0's true dur.
    k_pass0<<<dim3(GRID), dim3(512), 0, stream>>>(Tqb, X, cand, blkmint);
    k_pass0<<<dim3(GRID), dim3(512), 0, stream>>>(Tqb, X, cand, blkmint);
    k_sel<<<dim3(BQ), dim3(256), 0, stream>>>(cand, blkmint, Tq, X,
                                              q_indices, pre_indices, pre_weights, klv);
    k_out<<<dim3(1), dim3(256), 0, stream>>>(klv, W, (float*)d_out);
}

// Round 17
// 96.016 us; speedup vs baseline: 1.2227x; 1.2227x over previous
//
#include <hip/hip_runtime.h>
#include <math.h>

#define KNN 16
#define DIM 128
#define BQ 256
#define NDB 100000
#define GRID 512                 // k_pass0 blocks
#define RPP 32                   // rows per chunk
#define NCHUNK 3125              // 100000 / 32, exact
#define LONGB 53                 // blocks with 7 chunks (rest 6)
#define XB_STR 136               // ushorts per LDS B-row (128 + 8 pad)
#define MREG 8                   // GRID / 64
#define CAPS 256                 // k_sel candidate cap (worst case ~64)
#define TAU_INV 10.0f
#define EPSC 1e-8f
#define FBIG 3.402823e38f

typedef float f32x4 __attribute__((ext_vector_type(4)));
typedef __bf16 bf16x8 __attribute__((ext_vector_type(8)));
typedef unsigned short ushort;
typedef ushort ushort8 __attribute__((ext_vector_type(8)));

__device__ __forceinline__ ushort f32_to_bf16_rne(float v) {
    unsigned bits = __float_as_uint(v);
    return (ushort)((bits + 0x7FFFu + ((bits >> 16) & 1u)) >> 16);
}
__device__ __forceinline__ float packv(float v, int id) {
    return __uint_as_float((__float_as_uint(v) & 0xFFFFFF00u) | (unsigned)id);
}

// ---------------- Kernel A: Tq = q_batch @ W (f32 + bf16 copies) ----------------
__global__ void k_tq(const float* __restrict__ qb, const float* __restrict__ W,
                     float* __restrict__ Tq, ushort* __restrict__ Tqb) {
    int b = blockIdx.x, c = threadIdx.x;   // 128 threads
    __shared__ float qs[DIM];
    qs[c] = qb[b * DIM + c];
    __syncthreads();
    float acc = 0.f;
#pragma unroll 8
    for (int k = 0; k < DIM; ++k) acc = fmaf(qs[k], W[k * DIM + c], acc);
    Tq[b * DIM + c] = acc;
    Tqb[b * DIM + c] = f32_to_bf16_rne(acc);
}

// ---------------- Kernel B: MFMA pass w/ COMPUTE-DOUBLING PROBE ----------------
// The MFMA+insert block runs twice per chunk; 2nd copy feeds dummy regs kept
// alive via asm sink (no DCE, no output change). Staging/HBM unchanged.
// If dur ~2x => compute-bound; if ~1x => latency/BW-bound.
__global__ __launch_bounds__(512, 2)
void k_pass0(const ushort* __restrict__ Tqb, const float* __restrict__ X,
             float* __restrict__ cand, float* __restrict__ blkmin_t) {
    __shared__ ushort xb[2][RPP * XB_STR];
    __shared__ float xsq_lds[2][RPP];
    const int t = threadIdx.x;
    const int w = t >> 6, lane = t & 63;
    const int la = lane >> 4, lb = lane & 15;
    const int sr = t >> 4, sc = t & 15;
    const int bid = blockIdx.x;
    const int nph = (bid < LONGB) ? 7 : 6;

    bf16x8 afr[2][4];              // 32 queries x K=128 = 32 VGPRs, resident
#pragma unroll
    for (int mt = 0; mt < 2; ++mt)
#pragma unroll
        for (int ks = 0; ks < 4; ++ks)
            afr[mt][ks] = *reinterpret_cast<const bf16x8*>(
                Tqb + (size_t)(w * 32 + mt * 16 + lb) * DIM + ks * 32 + la * 8);

    {   // prolog: stage chunk 0 (f32 -> bf16 + xsq)
        const int rbase = bid * RPP;
        const float4* src = reinterpret_cast<const float4*>(X + (size_t)(rbase + sr) * DIM + sc * 8);
        float4 v0 = src[0], v1 = src[1];
        ushort8 o;
        o[0]=f32_to_bf16_rne(v0.x); o[1]=f32_to_bf16_rne(v0.y); o[2]=f32_to_bf16_rne(v0.z); o[3]=f32_to_bf16_rne(v0.w);
        o[4]=f32_to_bf16_rne(v1.x); o[5]=f32_to_bf16_rne(v1.y); o[6]=f32_to_bf16_rne(v1.z); o[7]=f32_to_bf16_rne(v1.w);
        *reinterpret_cast<ushort8*>(&xb[0][sr * XB_STR + sc * 8]) = o;
        float s = v0.x*v0.x + v0.y*v0.y + v0.z*v0.z + v0.w*v0.w
                + v1.x*v1.x + v1.y*v1.y + v1.z*v1.z + v1.w*v1.w;
        s += __shfl_xor(s, 1, 16); s += __shfl_xor(s, 2, 16);
        s += __shfl_xor(s, 4, 16); s += __shfl_xor(s, 8, 16);
        if (sc == 0) xsq_lds[0][sr] = s;
    }
    asm volatile("s_waitcnt lgkmcnt(0)" ::: "memory");
    __builtin_amdgcn_s_barrier();

    float t4_0[2][4], t4_1[2][4], t4_2[2][4], t4_3[2][4];
    float d4_0[2][4], d4_1[2][4], d4_2[2][4], d4_3[2][4];   // probe dummies
#pragma unroll
    for (int mt = 0; mt < 2; ++mt)
#pragma unroll
        for (int r = 0; r < 4; ++r) {
            t4_0[mt][r] = FBIG; t4_1[mt][r] = FBIG;
            t4_2[mt][r] = FBIG; t4_3[mt][r] = FBIG;
            d4_0[mt][r] = FBIG; d4_1[mt][r] = FBIG;
            d4_2[mt][r] = FBIG; d4_3[mt][r] = FBIG;
        }

#pragma unroll 1
    for (int p = 0; p < nph; ++p) {
        const int cur = p & 1, nxt = cur ^ 1;
        const int rb2 = (bid + ((p + 1) << 9)) << 5;
        float4 q0, q1;
        if (p + 1 < nph) {
            const float4* s2 = reinterpret_cast<const float4*>(X + (size_t)(rb2 + sr) * DIM + sc * 8);
            q0 = s2[0]; q1 = s2[1];
        }
#pragma unroll
        for (int nt = 0; nt < 2; ++nt) {
            const int row = nt * 16 + lb;
            bf16x8 bfr[4];
#pragma unroll
            for (int ks = 0; ks < 4; ++ks)
                bfr[ks] = *reinterpret_cast<const bf16x8*>(
                    &xb[cur][row * XB_STR + ks * 32 + la * 8]);
            const float xs = xsq_lds[cur][row];
            const int id = (((p << 1) | nt) << 4) | lb;   // 8-bit source id
            // ---- real compute ----
#pragma unroll
            for (int mt = 0; mt < 2; ++mt) {
                f32x4 acc = {0.f, 0.f, 0.f, 0.f};
#pragma unroll
                for (int ks = 0; ks < 4; ++ks)
                    acc = __builtin_amdgcn_mfma_f32_16x16x32_bf16(afr[mt][ks], bfr[ks], acc, 0, 0, 0);
#pragma unroll
                for (int r = 0; r < 4; ++r) {
                    float tv = packv(fmaf(-2.f, acc[r], xs), id);
                    float b0 = fminf(t4_0[mt][r], tv); tv = fmaxf(t4_0[mt][r], tv);
                    float b1 = fminf(t4_1[mt][r], tv); tv = fmaxf(t4_1[mt][r], tv);
                    float b2 = fminf(t4_2[mt][r], tv); tv = fmaxf(t4_2[mt][r], tv);
                    float b3 = fminf(t4_3[mt][r], tv);
                    t4_0[mt][r] = b0; t4_1[mt][r] = b1;
                    t4_2[mt][r] = b2; t4_3[mt][r] = b3;
                }
            }
            // ---- PROBE: duplicated compute into dummy regs (asm-sunk below) ----
#pragma unroll
            for (int mt = 0; mt < 2; ++mt) {
                f32x4 acc = {0.f, 0.f, 0.f, 0.f};
#pragma unroll
                for (int ks = 0; ks < 4; ++ks)
                    acc = __builtin_amdgcn_mfma_f32_16x16x32_bf16(afr[mt][ks], bfr[ks], acc, 0, 0, 0);
#pragma unroll
                for (int r = 0; r < 4; ++r) {
                    float tv = packv(fmaf(-2.f, acc[r], xs), id);
                    float b0 = fminf(d4_0[mt][r], tv); tv = fmaxf(d4_0[mt][r], tv);
                    float b1 = fminf(d4_1[mt][r], tv); tv = fmaxf(d4_1[mt][r], tv);
                    float b2 = fminf(d4_2[mt][r], tv); tv = fmaxf(d4_2[mt][r], tv);
                    float b3 = fminf(d4_3[mt][r], tv);
                    d4_0[mt][r] = b0; d4_1[mt][r] = b1;
                    d4_2[mt][r] = b2; d4_3[mt][r] = b3;
                }
            }
        }
        if (p + 1 < nph) {   // write-late staging of next chunk
            ushort8 o;
            o[0]=f32_to_bf16_rne(q0.x); o[1]=f32_to_bf16_rne(q0.y); o[2]=f32_to_bf16_rne(q0.z); o[3]=f32_to_bf16_rne(q0.w);
            o[4]=f32_to_bf16_rne(q1.x); o[5]=f32_to_bf16_rne(q1.y); o[6]=f32_to_bf16_rne(q1.z); o[7]=f32_to_bf16_rne(q1.w);
            *reinterpret_cast<ushort8*>(&xb[nxt][sr * XB_STR + sc * 8]) = o;
            float s = q0.x*q0.x + q0.y*q0.y + q0.z*q0.z + q0.w*q0.w
                    + q1.x*q1.x + q1.y*q1.y + q1.z*q1.z + q1.w*q1.w;
            s += __shfl_xor(s, 1, 16); s += __shfl_xor(s, 2, 16);
            s += __shfl_xor(s, 4, 16); s += __shfl_xor(s, 8, 16);
            if (sc == 0) xsq_lds[nxt][sr] = s;
            asm volatile("s_waitcnt lgkmcnt(0)" ::: "memory");
            __builtin_amdgcn_s_barrier();
        }
    }

    // sink the probe dummies (keeps duplicated MFMA/insert alive; writes nothing)
#pragma unroll
    for (int mt = 0; mt < 2; ++mt)
#pragma unroll
        for (int r = 0; r < 4; ++r)
            asm volatile("" :: "v"(d4_0[mt][r]), "v"(d4_1[mt][r]),
                               "v"(d4_2[mt][r]), "v"(d4_3[mt][r]));

    // epilogue: merge 16 lanes' sorted-4 lists (butterfly; bitonic half-clean + sort4)
#pragma unroll
    for (int mt = 0; mt < 2; ++mt)
#pragma unroll
        for (int r = 0; r < 4; ++r) {
            float a0 = t4_0[mt][r], a1 = t4_1[mt][r], a2 = t4_2[mt][r], a3 = t4_3[mt][r];
#pragma unroll
            for (int m = 1; m <= 8; m <<= 1) {
                float b0 = __shfl_xor(a0, m, 16), b1 = __shfl_xor(a1, m, 16);
                float b2 = __shfl_xor(a2, m, 16), b3 = __shfl_xor(a3, m, 16);
                float l0 = fminf(a0, b3), l1 = fminf(a1, b2);
                float l2 = fminf(a2, b1), l3 = fminf(a3, b0);
                float u;
                u = fminf(l0, l2); l2 = fmaxf(l0, l2); l0 = u;
                u = fminf(l1, l3); l3 = fmaxf(l1, l3); l1 = u;
                u = fminf(l0, l1); l1 = fmaxf(l0, l1); l0 = u;
                u = fminf(l2, l3); l3 = fmaxf(l2, l3); l2 = u;
                a0 = l0; a1 = l1; a2 = l2; a3 = l3;
            }
            if (lb == 0) {
                const int q = w * 32 + mt * 16 + la * 4 + r;
                f32x4 o4 = {a0, a1, a2, a3};
                *reinterpret_cast<f32x4*>(cand + (size_t)q * (GRID * 4) + bid * 4) = o4;
                blkmin_t[(size_t)q * GRID + bid] = a0;
            }
        }
}

// ---------------- Kernel C: tau + filter + rank select + exact l2 + softmax + KL ----------------
__global__ __launch_bounds__(256)
void k_sel(const float* __restrict__ cand, const float* __restrict__ blkmin_t,
           const float* __restrict__ Tq, const float* __restrict__ X,
           const int* __restrict__ q_indices,
           const int* __restrict__ pre_indices,
           const float* __restrict__ pre_weights,
           float* __restrict__ klv) {
    const int q = blockIdx.x, t = threadIdx.x;
    __shared__ float tau_s;
    __shared__ int cnt_s;
    __shared__ float cv[CAPS]; __shared__ int ce[CAPS];
    __shared__ int post_idx[KNN];
    __shared__ float l2s[KNN];
    __shared__ float post_w[KNN];
    __shared__ int u_idx[2 * KNN]; __shared__ float u_p[2 * KNN]; __shared__ float u_q[2 * KNN];
    __shared__ int cnt2_s;

    if (t == 0) cnt_s = 0;
    if (t < KNN) post_idx[t] = 0;
    if (t < 64) {   // wave 0: tau = exact 16th smallest packed block-min
        float m[MREG];
#pragma unroll
        for (int k = 0; k < MREG; ++k)
            m[k] = blkmin_t[(size_t)q * GRID + t + (k << 6)];
        float tv = FBIG;
        for (int e = 0; e < KNN; ++e) {
            float best = m[0];
#pragma unroll
            for (int k = 1; k < MREG; ++k) best = fminf(best, m[k]);
            float b = best;
#pragma unroll
            for (int s = 1; s < 64; s <<= 1) b = fminf(b, __shfl_xor(b, s, 64));
            tv = b;
            unsigned long long has = __ballot(best == b);
            int src = (int)__builtin_ctzll(has);
            if (t == src) {
                bool dn = false;
#pragma unroll
                for (int k = 0; k < MREG; ++k) {
                    bool hit = !dn && (m[k] == b);
                    if (hit) { m[k] = FBIG; dn = true; }
                }
            }
        }
        if (t == 0) tau_s = tv;
    }
    __syncthreads();
    const float tau = tau_s;

    for (int e = t; e < GRID * 4; e += 256) {
        float pv = cand[(size_t)q * (GRID * 4) + e];
        if (pv <= tau) {
            int pos = atomicAdd(&cnt_s, 1);
            if (pos < CAPS) { cv[pos] = pv; ce[pos] = e; }
        }
    }
    __syncthreads();
    int n = cnt_s; n = (n > CAPS) ? CAPS : n;

    for (int e = t; e < n; e += 256) {
        float v = cv[e]; int id = ce[e];
        int r = 0;
        for (int i2 = 0; i2 < n; ++i2) {
            float vi = cv[i2];
            r += (vi < v) || (vi == v && ce[i2] < id);
        }
        if (r < KNN) {
            int bid = id >> 2;
            int sid = __float_as_uint(v) & 255;           // ((p*2+nt)<<4)|lb
            int j = (bid + (sid >> 5) * GRID) * RPP + ((sid >> 4) & 1) * 16 + (sid & 15);
            post_idx[r] = j;
        }
    }
    __syncthreads();

    {   // exact f32 l2 for the selected 16 (16 threads x 8 dims each)
        int nn = t >> 4, l = t & 15;
        int idx = post_idx[nn];
        idx = (idx < 0) ? 0 : ((idx >= NDB) ? NDB - 1 : idx);
        const float* tr = Tq + q * DIM + l * 8;
        const float* xr = X + (size_t)idx * DIM + l * 8;
        float s = 0.f;
#pragma unroll
        for (int kk = 0; kk < 8; ++kk) { float df = tr[kk] - xr[kk]; s = fmaf(df, df, s); }
#pragma unroll
        for (int m = 1; m < 16; m <<= 1) s += __shfl_xor(s, m, 64);
        if (l == 0) l2s[nn] = s;
    }
    __syncthreads();

    if (t < 64) {   // wave-parallel softmax over the 16 l2 values
        float v = (t < KNN) ? (-l2s[t] * TAU_INV) : -FBIG;
        float mx = v;
#pragma unroll
        for (int m = 1; m < 16; m <<= 1) mx = fmaxf(mx, __shfl_xor(mx, m, 64));
        float e = (t < KNN) ? expf(v - mx) : 0.f;
        float sum = e;
#pragma unroll
        for (int m = 1; m < 16; m <<= 1) sum += __shfl_xor(sum, m, 64);
        if (t < KNN) post_w[t] = e / sum;
    }
    __syncthreads();

    if (t == 0) {   // union build: serial (order-sensitive last-wins)
        int qi = q_indices[q];
        int cnt2 = KNN;
        for (int i = 0; i < KNN; ++i) { u_idx[i] = post_idx[i]; u_q[i] = post_w[i]; u_p[i] = 0.f; }
        for (int m = 0; m < KNN; ++m) {
            int pi = pre_indices[qi * KNN + m];
            float pwm = pre_weights[qi * KNN + m];
            int f = -1;
            for (int s2 = 0; s2 < cnt2; ++s2) if (u_idx[s2] == pi) { f = s2; break; }
            if (f >= 0) u_p[f] = pwm;
            else { u_idx[cnt2] = pi; u_p[cnt2] = pwm; u_q[cnt2] = 0.f; ++cnt2; }
        }
        cnt2_s = cnt2;
    }
    __syncthreads();

    if (t < 64) {   // wave-parallel KL: T/Zp - log Zp + log Zq
        int cnt2 = cnt2_s;
        float pe = 0.f, qe = 0.f, te = 0.f;
        if (t < cnt2) {
            pe = fmaxf(u_p[t], EPSC);
            qe = fmaxf(u_q[t], EPSC);
            te = pe * (logf(pe) - logf(qe));
        }
        float Zp = pe, Zq = qe, T = te;
#pragma unroll
        for (int m = 1; m < 64; m <<= 1) {
            Zp += __shfl_xor(Zp, m, 64);
            Zq += __shfl_xor(Zq, m, 64);
            T  += __shfl_xor(T, m, 64);
        }
        if (t == 0) klv[q] = T / Zp - logf(Zp) + logf(Zq);
    }
}

// ---------------- Kernel D: final reduction + outputs ----------------
__global__ void k_out(const float* __restrict__ kl, const float* __restrict__ W,
                      float* __restrict__ out) {
    int t = threadIdx.x;
    float s_kl = (t < BQ) ? kl[t] : 0.f;
    float s_w = 0.f;
    for (int i = t; i < DIM * DIM; i += 256) { float w = W[i]; s_w = fmaf(w, w, s_w); }
#pragma unroll
    for (int m = 32; m >= 1; m >>= 1) {
        s_kl += __shfl_xor(s_kl, m, 64);
        s_w += __shfl_xor(s_w, m, 64);
    }
    __shared__ float rk[4], rw[4];
    if ((t & 63) == 0) { rk[t >> 6] = s_kl; rw[t >> 6] = s_w; }
    __syncthreads();
    if (t == 0) {
        float kls = rk[0] + rk[1] + rk[2] + rk[3];
        float wss = rw[0] + rw[1] + rw[2] + rw[3];
        float knn = kls * (1.0f / BQ);
        float reg = 0.5f * wss;
        out[0] = 1.0f * knn + 1e-4f * reg;
        out[1] = 0.f;
        out[2] = knn;
    }
}

extern "C" void kernel_launch(void* const* d_in, const int* in_sizes, int n_in,
                              void* d_out, int out_size, void* d_ws, size_t ws_size,
                              hipStream_t stream) {
    const float* q_batch     = (const float*)d_in[0];
    const int*   q_indices   = (const int*)d_in[1];
    const float* X           = (const float*)d_in[2];
    const float* W           = (const float*)d_in[3];
    const int*   pre_indices = (const int*)d_in[4];
    const float* pre_weights = (const float*)d_in[5];

    char* ws = (char*)d_ws;
    float*  Tq      = (float*)(ws);                  // 128KB
    ushort* Tqb     = (ushort*)(ws + 131072);        // 64KB
    float*  klv     = (float*)(ws + 196608);         // 1KB
    float*  blkmint = (float*)(ws + 262144);         // 256*512*4 = 512KB
    float*  cand    = (float*)(ws + 1048576);        // 256*2048*4 = 2MB

    k_tq<<<dim3(BQ), dim3(DIM), 0, stream>>>(q_batch, W, Tq, Tqb);
    k_pass0<<<dim3(GRID), dim3(512), 0, stream>>>(Tqb, X, cand, blkmint);
    k_sel<<<dim3(BQ), dim3(256), 0, stream>>>(cand, blkmint, Tq, X,
                                              q_indices, pre_indices, pre_weights, klv);
    k_out<<<dim3(1), dim3(256), 0, stream>>>(klv, W, (float*)d_out);
}

// Round 18
// 63.434 us; speedup vs baseline: 1.8507x; 1.5136x over previous
//
#include <hip/hip_runtime.h>
#include <math.h>

#define KNN 16
#define DIM 128
#define BQ 256
#define NDB 100000
#define GRID 512                 // k_pass0 blocks
#define RPP 32                   // rows per chunk
#define NCHUNK 3125              // 100000 / 32, exact
#define LONGB 53                 // blocks with 7 chunks (rest 6)
#define XB_STR 136               // ushorts per LDS B-row (128 + 8 pad)
#define MREG 8                   // GRID / 64
#define CAPS 256                 // k_sel candidate cap (worst case ~64)
#define TAU_INV 10.0f
#define EPSC 1e-8f
#define FBIG 3.402823e38f

typedef float f32x4 __attribute__((ext_vector_type(4)));
typedef __bf16 bf16x8 __attribute__((ext_vector_type(8)));
typedef unsigned short ushort;
typedef ushort ushort8 __attribute__((ext_vector_type(8)));
typedef unsigned int uint4v __attribute__((ext_vector_type(4)));

__device__ __forceinline__ ushort f32_to_bf16_rne(float v) {
    unsigned bits = __float_as_uint(v);
    return (ushort)((bits + 0x7FFFu + ((bits >> 16) & 1u)) >> 16);
}
// pack two f32 -> two truncated bf16 in one u32 (low = lo's bf16): ~v_perm
__device__ __forceinline__ unsigned pack2(float lo, float hi) {
    return (__float_as_uint(hi) & 0xFFFF0000u) | (__float_as_uint(lo) >> 16);
}
__device__ __forceinline__ float packv(float v, int id) {
    return __uint_as_float((__float_as_uint(v) & 0xFFFFFF00u) | (unsigned)id);
}

// ---------------- Kernel A: Tq = q_batch @ W (f32 + bf16 copies) ----------------
__global__ void k_tq(const float* __restrict__ qb, const float* __restrict__ W,
                     float* __restrict__ Tq, ushort* __restrict__ Tqb) {
    int b = blockIdx.x, c = threadIdx.x;   // 128 threads
    __shared__ float qs[DIM];
    qs[c] = qb[b * DIM + c];
    __syncthreads();
    float acc = 0.f;
#pragma unroll 8
    for (int k = 0; k < DIM; ++k) acc = fmaf(qs[k], W[k * DIM + c], acc);
    Tq[b * DIM + c] = acc;
    Tqb[b * DIM + c] = f32_to_bf16_rne(acc);
}

// ---------------- Kernel B: MFMA pass, per-lane packed top-2, block top-4 ----------------
__global__ __launch_bounds__(512, 2)
void k_pass0(const ushort* __restrict__ Tqb, const float* __restrict__ X,
             float* __restrict__ cand, float* __restrict__ blkmin_t) {
    __shared__ ushort xb[2][RPP * XB_STR];
    __shared__ float xsq_lds[2][RPP];
    const int t = threadIdx.x;
    const int w = t >> 6, lane = t & 63;
    const int la = lane >> 4, lb = lane & 15;
    const int sr = t >> 4, sc = t & 15;
    const int bid = blockIdx.x;
    const int nph = (bid < LONGB) ? 7 : 6;

    bf16x8 afr[2][4];              // 32 queries x K=128 = 32 VGPRs, resident
#pragma unroll
    for (int mt = 0; mt < 2; ++mt)
#pragma unroll
        for (int ks = 0; ks < 4; ++ks)
            afr[mt][ks] = *reinterpret_cast<const bf16x8*>(
                Tqb + (size_t)(w * 32 + mt * 16 + lb) * DIM + ks * 32 + la * 8);

    {   // prolog: stage chunk 0 (f32 -> trunc-bf16 pack + xsq)
        const int rbase = bid * RPP;
        const float4* src = reinterpret_cast<const float4*>(X + (size_t)(rbase + sr) * DIM + sc * 8);
        float4 v0 = src[0], v1 = src[1];
        uint4v o = { pack2(v0.x, v0.y), pack2(v0.z, v0.w),
                     pack2(v1.x, v1.y), pack2(v1.z, v1.w) };
        *reinterpret_cast<uint4v*>(&xb[0][sr * XB_STR + sc * 8]) = o;
        float s = v0.x*v0.x + v0.y*v0.y + v0.z*v0.z + v0.w*v0.w
                + v1.x*v1.x + v1.y*v1.y + v1.z*v1.z + v1.w*v1.w;
        s += __shfl_xor(s, 1, 16); s += __shfl_xor(s, 2, 16);
        s += __shfl_xor(s, 4, 16); s += __shfl_xor(s, 8, 16);
        if (sc == 0) xsq_lds[0][sr] = s;
    }
    asm volatile("s_waitcnt lgkmcnt(0)" ::: "memory");
    __builtin_amdgcn_s_barrier();

    // packed top-2 per (mt, r): ascending t2_0 <= t2_1 (16 VGPRs)
    float t2_0[2][4], t2_1[2][4];
#pragma unroll
    for (int mt = 0; mt < 2; ++mt)
#pragma unroll
        for (int r = 0; r < 4; ++r) { t2_0[mt][r] = FBIG; t2_1[mt][r] = FBIG; }

#pragma unroll 1
    for (int p = 0; p < nph; ++p) {
        const int cur = p & 1, nxt = cur ^ 1;
        const int rb2 = (bid + ((p + 1) << 9)) << 5;
        float4 q0, q1;
        if (p + 1 < nph) {
            const float4* s2 = reinterpret_cast<const float4*>(X + (size_t)(rb2 + sr) * DIM + sc * 8);
            q0 = s2[0]; q1 = s2[1];
        }
#pragma unroll
        for (int nt = 0; nt < 2; ++nt) {
            const int row = nt * 16 + lb;
            bf16x8 bfr[4];
#pragma unroll
            for (int ks = 0; ks < 4; ++ks)
                bfr[ks] = *reinterpret_cast<const bf16x8*>(
                    &xb[cur][row * XB_STR + ks * 32 + la * 8]);
            const float xs = xsq_lds[cur][row];
            const int id = (((p << 1) | nt) << 4) | lb;   // 8-bit source id
#pragma unroll
            for (int mt = 0; mt < 2; ++mt) {
                f32x4 acc = {0.f, 0.f, 0.f, 0.f};
#pragma unroll
                for (int ks = 0; ks < 4; ++ks)
                    acc = __builtin_amdgcn_mfma_f32_16x16x32_bf16(afr[mt][ks], bfr[ks], acc, 0, 0, 0);
#pragma unroll
                for (int r = 0; r < 4; ++r) {
                    float pv = packv(fmaf(-2.f, acc[r], xs), id);
                    // 3-op top-2 insert
                    float b0 = fminf(t2_0[mt][r], pv);
                    float hi = fmaxf(t2_0[mt][r], pv);
                    t2_1[mt][r] = fminf(t2_1[mt][r], hi);
                    t2_0[mt][r] = b0;
                }
            }
        }
        if (p + 1 < nph) {   // write-late staging of next chunk
            uint4v o = { pack2(q0.x, q0.y), pack2(q0.z, q0.w),
                         pack2(q1.x, q1.y), pack2(q1.z, q1.w) };
            *reinterpret_cast<uint4v*>(&xb[nxt][sr * XB_STR + sc * 8]) = o;
            float s = q0.x*q0.x + q0.y*q0.y + q0.z*q0.z + q0.w*q0.w
                    + q1.x*q1.x + q1.y*q1.y + q1.z*q1.z + q1.w*q1.w;
            s += __shfl_xor(s, 1, 16); s += __shfl_xor(s, 2, 16);
            s += __shfl_xor(s, 4, 16); s += __shfl_xor(s, 8, 16);
            if (sc == 0) xsq_lds[nxt][sr] = s;
            asm volatile("s_waitcnt lgkmcnt(0)" ::: "memory");
            __builtin_amdgcn_s_barrier();
        }
    }

    // epilogue: merge 16 lanes' sorted-2 lists (pad to 4 with FBIG; same butterfly)
#pragma unroll
    for (int mt = 0; mt < 2; ++mt)
#pragma unroll
        for (int r = 0; r < 4; ++r) {
            float a0 = t2_0[mt][r], a1 = t2_1[mt][r], a2 = FBIG, a3 = FBIG;
#pragma unroll
            for (int m = 1; m <= 8; m <<= 1) {
                float b0 = __shfl_xor(a0, m, 16), b1 = __shfl_xor(a1, m, 16);
                float b2 = __shfl_xor(a2, m, 16), b3 = __shfl_xor(a3, m, 16);
                float l0 = fminf(a0, b3), l1 = fminf(a1, b2);
                float l2 = fminf(a2, b1), l3 = fminf(a3, b0);
                float u;
                u = fminf(l0, l2); l2 = fmaxf(l0, l2); l0 = u;
                u = fminf(l1, l3); l3 = fmaxf(l1, l3); l1 = u;
                u = fminf(l0, l1); l1 = fmaxf(l0, l1); l0 = u;
                u = fminf(l2, l3); l3 = fmaxf(l2, l3); l2 = u;
                a0 = l0; a1 = l1; a2 = l2; a3 = l3;
            }
            if (lb == 0) {
                const int q = w * 32 + mt * 16 + la * 4 + r;
                f32x4 o4 = {a0, a1, a2, a3};
                *reinterpret_cast<f32x4*>(cand + (size_t)q * (GRID * 4) + bid * 4) = o4;
                blkmin_t[(size_t)q * GRID + bid] = a0;
            }
        }
}

// ---------------- Kernel C: tau + filter + rank select + l2 + softmax + wave-union KL ----------------
__global__ __launch_bounds__(512)
void k_sel(const float* __restrict__ cand, const float* __restrict__ blkmin_t,
           const float* __restrict__ Tq, const float* __restrict__ X,
           const int* __restrict__ q_indices,
           const int* __restrict__ pre_indices,
           const float* __restrict__ pre_weights,
           float* __restrict__ klv) {
    const int q = blockIdx.x, t = threadIdx.x;
    __shared__ float tau_s;
    __shared__ int cnt_s;
    __shared__ float cv[CAPS]; __shared__ int ce[CAPS];
    __shared__ int post_idx[KNN];
    __shared__ float l2s[KNN];
    __shared__ float post_w[KNN];

    if (t == 0) cnt_s = 0;
    if (t < KNN) post_idx[t] = 0;
    if (t < 64) {   // wave 0: tau = exact 16th smallest packed block-min
        float m[MREG];
#pragma unroll
        for (int k = 0; k < MREG; ++k)
            m[k] = blkmin_t[(size_t)q * GRID + t + (k << 6)];
        float tv = FBIG;
        for (int e = 0; e < KNN; ++e) {
            float best = m[0];
#pragma unroll
            for (int k = 1; k < MREG; ++k) best = fminf(best, m[k]);
            float b = best;
#pragma unroll
            for (int s = 1; s < 64; s <<= 1) b = fminf(b, __shfl_xor(b, s, 64));
            tv = b;
            unsigned long long has = __ballot(best == b);
            int src = (int)__builtin_ctzll(has);
            if (t == src) {
                bool dn = false;
#pragma unroll
                for (int k = 0; k < MREG; ++k) {
                    bool hit = !dn && (m[k] == b);
                    if (hit) { m[k] = FBIG; dn = true; }
                }
            }
        }
        if (t == 0) tau_s = tv;
    }
    __syncthreads();
    const float tau = tau_s;

    for (int e = t; e < GRID * 4; e += 512) {
        float pv = cand[(size_t)q * (GRID * 4) + e];
        if (pv <= tau) {
            int pos = atomicAdd(&cnt_s, 1);
            if (pos < CAPS) { cv[pos] = pv; ce[pos] = e; }
        }
    }
    __syncthreads();
    int n = cnt_s; n = (n > CAPS) ? CAPS : n;

    for (int e = t; e < n; e += 512) {
        float v = cv[e]; int id = ce[e];
        int r = 0;
        for (int i2 = 0; i2 < n; ++i2) {
            float vi = cv[i2];
            r += (vi < v) || (vi == v && ce[i2] < id);
        }
        if (r < KNN) {
            int bid = id >> 2;
            int sid = __float_as_uint(v) & 255;           // ((p*2+nt)<<4)|lb
            int j = (bid + (sid >> 5) * GRID) * RPP + ((sid >> 4) & 1) * 16 + (sid & 15);
            post_idx[r] = j;
        }
    }
    __syncthreads();

    if (t < 256) {   // exact f32 l2 for the selected 16 (16 threads x 8 dims each)
        int nn = t >> 4, l = t & 15;
        int idx = post_idx[nn];
        idx = (idx < 0) ? 0 : ((idx >= NDB) ? NDB - 1 : idx);
        const float* tr = Tq + q * DIM + l * 8;
        const float* xr = X + (size_t)idx * DIM + l * 8;
        float s = 0.f;
#pragma unroll
        for (int kk = 0; kk < 8; ++kk) { float df = tr[kk] - xr[kk]; s = fmaf(df, df, s); }
#pragma unroll
        for (int m = 1; m < 16; m <<= 1) s += __shfl_xor(s, m, 64);
        if (l == 0) l2s[nn] = s;
    }
    __syncthreads();

    if (t < 64) {   // wave 0: softmax + in-register union (last-wins) + KL
        float v = (t < KNN) ? (-l2s[t] * TAU_INV) : -FBIG;
        float mx = v;
#pragma unroll
        for (int m = 1; m < 16; m <<= 1) mx = fmaxf(mx, __shfl_xor(mx, m, 64));
        float e = (t < KNN) ? expf(v - mx) : 0.f;
        float sum = e;
#pragma unroll
        for (int m = 1; m < 16; m <<= 1) sum += __shfl_xor(sum, m, 64);
        if (t < KNN) post_w[t] = e / sum;

        // in-register union: lane t holds entry t (post first, pre appended)
        int ui = (t < KNN) ? post_idx[t] : -1;
        float uq = (t < KNN) ? post_w[t] : 0.f;
        float up = 0.f;
        int cnt2 = KNN;
        const int qi = q_indices[q];
        for (int m = 0; m < KNN; ++m) {
            int pi = pre_indices[qi * KNN + m];
            float pwm = pre_weights[qi * KNN + m];
            unsigned long long mm = __ballot(ui == pi);
            if (mm) {
                if (t == (int)__builtin_ctzll(mm)) up = pwm;   // last-wins overwrite
            } else {
                if (t == cnt2) { ui = pi; up = pwm; uq = 0.f; }
                ++cnt2;
            }
        }
        float pe = 0.f, qe = 0.f, te = 0.f;
        if (t < cnt2) {
            pe = fmaxf(up, EPSC);
            qe = fmaxf(uq, EPSC);
            te = pe * (logf(pe) - logf(qe));
        }
        float Zp = pe, Zq = qe, T = te;
#pragma unroll
        for (int m = 1; m < 64; m <<= 1) {
            Zp += __shfl_xor(Zp, m, 64);
            Zq += __shfl_xor(Zq, m, 64);
            T  += __shfl_xor(T, m, 64);
        }
        if (t == 0) klv[q] = T / Zp - logf(Zp) + logf(Zq);
    }
}

// ---------------- Kernel D: final reduction + outputs ----------------
__global__ void k_out(const float* __restrict__ kl, const float* __restrict__ W,
                      float* __restrict__ out) {
    int t = threadIdx.x;
    float s_kl = (t < BQ) ? kl[t] : 0.f;
    float s_w = 0.f;
    for (int i = t; i < DIM * DIM; i += 256) { float w = W[i]; s_w = fmaf(w, w, s_w); }
#pragma unroll
    for (int m = 32; m >= 1; m >>= 1) {
        s_kl += __shfl_xor(s_kl, m, 64);
        s_w += __shfl_xor(s_w, m, 64);
    }
    __shared__ float rk[4], rw[4];
    if ((t & 63) == 0) { rk[t >> 6] = s_kl; rw[t >> 6] = s_w; }
    __syncthreads();
    if (t == 0) {
        float kls = rk[0] + rk[1] + rk[2] + rk[3];
        float wss = rw[0] + rw[1] + rw[2] + rw[3];
        float knn = kls * (1.0f / BQ);
        float reg = 0.5f * wss;
        out[0] = 1.0f * knn + 1e-4f * reg;
        out[1] = 0.f;
        out[2] = knn;
    }
}

extern "C" void kernel_launch(void* const* d_in, const int* in_sizes, int n_in,
                              void* d_out, int out_size, void* d_ws, size_t ws_size,
                              hipStream_t stream) {
    const float* q_batch     = (const float*)d_in[0];
    const int*   q_indices   = (const int*)d_in[1];
    const float* X           = (const float*)d_in[2];
    const float* W           = (const float*)d_in[3];
    const int*   pre_indices = (const int*)d_in[4];
    const float* pre_weights = (const float*)d_in[5];

    char* ws = (char*)d_ws;
    float*  Tq      = (float*)(ws);                  // 128KB
    ushort* Tqb     = (ushort*)(ws + 131072);        // 64KB
    float*  klv     = (float*)(ws + 196608);         // 1KB
    float*  blkmint = (float*)(ws + 262144);         // 256*512*4 = 512KB
    float*  cand    = (float*)(ws + 1048576);        // 256*2048*4 = 2MB

    k_tq<<<dim3(BQ), dim3(DIM), 0, stream>>>(q_batch, W, Tq, Tqb);
    k_pass0<<<dim3(GRID), dim3(512), 0, stream>>>(Tqb, X, cand, blkmint);
    k_sel<<<dim3(BQ), dim3(512), 0, stream>>>(cand, blkmint, Tq, X,
                                              q_indices, pre_indices, pre_weights, klv);
    k_out<<<dim3(1), dim3(256), 0, stream>>>(klv, W, (float*)d_out);
}